// Round 7
// baseline (242.199 us; speedup 1.0000x reference)
//
#include <hip/hip_runtime.h>
#include <hip/hip_bf16.h>

// SurfaceLoss: 16x256x256 grid through 3->128->128->128->1 tanh MLP, MSE vs images.
// R7: (a) fence-free last-block reduction (atomics only; barrier vmcnt-drain gives
//     ordering; agent-scope atomic LOADS for the final read — no L2 flush anywhere),
//     eliminating the finish dispatch (~20us gap). (b) tanh: v_rcp replaced by
//     bit-trick reciprocal + 1 Newton (full-rate ops, same live-reg count; zk
//     clamped <=88 so the integer seed stays finite).
//     Proven base: R2/R6 main body, (512,8), LDA 136, KS-folded exp2 tanh.

#define BATCH 16
#define LDA 136                 // padded LDS row stride (bf16 elems)
#define STEP (256.0f / 255.0f)  // linspace(-128,128,256) step
#define KS 2.8853900817779268f  // 2*log2(e): tanh(z) = 1 - 2/(exp2(KS*z)+1)

typedef __bf16 v8bf __attribute__((ext_vector_type(8)));
typedef float  v4f  __attribute__((ext_vector_type(4)));

__device__ __forceinline__ unsigned short f2bf(float f) {
    unsigned int u = __float_as_uint(f);
    unsigned int r = (u + 0x7fffu + ((u >> 16) & 1u)) >> 16;
    return (unsigned short)r;
}

#if __has_builtin(__builtin_amdgcn_cvt_pk_bf16_f32)
__device__ __forceinline__ unsigned int pack2bf(float a, float b) {
    auto p = __builtin_amdgcn_cvt_pk_bf16_f32(a, b);   // lo=a, hi=b
    union { decltype(p) v; unsigned int u; } c; c.v = p;
    return c.u;
}
#else
__device__ __forceinline__ unsigned int pack2bf(float a, float b) {
    return (unsigned)f2bf(a) | ((unsigned)f2bf(b) << 16);
}
#endif

// input pre-scaled by KS. tanh(z) = 1 - 2/(exp2(zk)+1).
// Reciprocal via bit-trick seed + 1 Newton (all full-rate); clamp keeps e1 finite
// so the integer seed is valid (exp2(88) huge but finite; tanh saturates anyway).
__device__ __forceinline__ float tanh_pre(float zk) {
    float e1 = __builtin_amdgcn_exp2f(fminf(zk, 88.f)) + 1.f;
    float r  = __uint_as_float(0x7EF311C3u - __float_as_uint(e1));
    r = r * fmaf(-e1, r, 2.f);          // 1 Newton: ~0.25% max rel err
    return fmaf(-2.f, r, 1.f);
}

// ---- prep: W2,W3 (128x128 fp32 [k][n]) -> bf16 [n][k] pre-scaled by KS;
//      zero partials + counter ----
__global__ __launch_bounds__(256) void prep_kernel(
    const float* __restrict__ W2, const float* __restrict__ W3,
    unsigned short* __restrict__ w2t, unsigned short* __restrict__ w3t,
    float* __restrict__ partials, unsigned int* __restrict__ counter)
{
    int o = blockIdx.x * 256 + threadIdx.x;
    if (o < 1024) partials[o] = 0.f;
    if (o == 0) *counter = 0u;
    const float* src = (o < 16384) ? W2 : W3;
    unsigned short* dst = (o < 16384) ? w2t : w3t;
    int e = o & 16383;
    int k = e >> 7, n = e & 127;
    dst[n * 128 + k] = f2bf(src[e] * KS);
}

// ---- main: one block (512 thr, 8 waves) = 128 consecutive pixels of one image row ----
__global__ __launch_bounds__(512, 8) void main_kernel(
    const float* __restrict__ images,
    const float* __restrict__ W1, const float* __restrict__ b1,
    const float* __restrict__ b2, const float* __restrict__ b3,
    const float* __restrict__ W4, const float* __restrict__ b4,
    const int*   __restrict__ np,
    const unsigned short* __restrict__ w2t,
    const unsigned short* __restrict__ w3t,
    float* __restrict__ partials, unsigned int* __restrict__ counter,
    float* __restrict__ out)
{
    __shared__ unsigned short A[128 * LDA];
    __shared__ float red[8];
    __shared__ unsigned int isLastS;

    const int tid  = threadIdx.x;
    const int lane = tid & 63;
    const int w    = tid >> 6;        // wave 0..7, owns 16 output cols
    const int l15  = lane & 15;
    const int quad = lane >> 4;

    const int bid = blockIdx.x;
    const int b   = bid >> 9;          // 512 blocks per image
    const int rem = bid & 511;
    const int r   = rem >> 1;          // image row (x index)
    const int c0  = (rem & 1) << 7;    // y base

    const float tv = (float)(b + np[0] * BATCH);
    const float xv = -128.f + (float)r * STEP;

    // ---- layer 1 (fp32, pre-scaled by KS): each thread 4 cols x 8 points ----
    {
        const int lo = tid & 31, hi = tid >> 5;
        const int j0 = lo * 4, p0 = hi * 8;
        float4 wx = *(const float4*)(W1 + j0);
        float4 wy = *(const float4*)(W1 + 128 + j0);
        float4 wt = *(const float4*)(W1 + 256 + j0);
        float4 bb = *(const float4*)(b1 + j0);
        float cj0 = KS * fmaf(xv, wx.x, fmaf(tv, wt.x, bb.x));
        float cj1 = KS * fmaf(xv, wx.y, fmaf(tv, wt.y, bb.y));
        float cj2 = KS * fmaf(xv, wx.z, fmaf(tv, wt.z, bb.z));
        float cj3 = KS * fmaf(xv, wx.w, fmaf(tv, wt.w, bb.w));
        float wy0 = KS * wy.x, wy1 = KS * wy.y, wy2 = KS * wy.z, wy3 = KS * wy.w;
        #pragma unroll
        for (int pi = 0; pi < 8; ++pi) {
            const int p = p0 + pi;
            const float yv = fmaf((float)(c0 + p), STEP, -128.f);
            float t0 = tanh_pre(fmaf(yv, wy0, cj0));
            float t1 = tanh_pre(fmaf(yv, wy1, cj1));
            float t2 = tanh_pre(fmaf(yv, wy2, cj2));
            float t3 = tanh_pre(fmaf(yv, wy3, cj3));
            uint2 u = make_uint2(pack2bf(t0, t1), pack2bf(t2, t3));
            *(uint2*)&A[p * LDA + j0] = u;   // 8B store, conflict-free
        }
    }
    __syncthreads();

    const int colw = w * 16 + l15;     // this lane's output column

    // ---- W2 B-fragments from L2 ([n][k] layout, pre-scaled) ----
    v8bf wf[4];
    #pragma unroll
    for (int ks = 0; ks < 4; ++ks)
        wf[ks] = *(const v8bf*)(w2t + colw * 128 + ks * 32 + quad * 8);

    // ---- layer 2 MFMA ----
    v4f acc[8];
    #pragma unroll
    for (int mt = 0; mt < 8; ++mt) acc[mt] = (v4f){0.f, 0.f, 0.f, 0.f};
    #pragma unroll
    for (int ks = 0; ks < 4; ++ks) {
        #pragma unroll
        for (int mt = 0; mt < 8; ++mt) {
            v8bf af = *(const v8bf*)&A[(mt * 16 + l15) * LDA + ks * 32 + quad * 8];
            acc[mt] = __builtin_amdgcn_mfma_f32_16x16x32_bf16(af, wf[ks], acc[mt], 0, 0, 0);
        }
    }

    // prefetch W3 fragments
    v8bf w3f[4];
    #pragma unroll
    for (int ks = 0; ks < 4; ++ks)
        w3f[ks] = *(const v8bf*)(w3t + colw * 128 + ks * 32 + quad * 8);
    __syncthreads();   // all waves done reading A

    // ---- epilogue 2: tanh(acc + KS*b2) -> A (acc already KS-scaled) ----
    {
        float biK = b2[colw] * KS;
        #pragma unroll
        for (int mt = 0; mt < 8; ++mt) {
            float t0 = tanh_pre(acc[mt][0] + biK);
            float t1 = tanh_pre(acc[mt][1] + biK);
            float t2 = tanh_pre(acc[mt][2] + biK);
            float t3 = tanh_pre(acc[mt][3] + biK);
            unsigned u01 = pack2bf(t0, t1);
            unsigned u23 = pack2bf(t2, t3);
            int rowb = (mt * 16 + quad * 4) * LDA + colw;
            A[rowb]           = (unsigned short)u01;
            A[rowb + LDA]     = (unsigned short)(u01 >> 16);
            A[rowb + 2 * LDA] = (unsigned short)u23;
            A[rowb + 3 * LDA] = (unsigned short)(u23 >> 16);
        }
    }
    __syncthreads();

    // ---- layer 3 MFMA ----
    #pragma unroll
    for (int mt = 0; mt < 8; ++mt) acc[mt] = (v4f){0.f, 0.f, 0.f, 0.f};
    #pragma unroll
    for (int ks = 0; ks < 4; ++ks) {
        #pragma unroll
        for (int mt = 0; mt < 8; ++mt) {
            v8bf af = *(const v8bf*)&A[(mt * 16 + l15) * LDA + ks * 32 + quad * 8];
            acc[mt] = __builtin_amdgcn_mfma_f32_16x16x32_bf16(af, w3f[ks], acc[mt], 0, 0, 0);
        }
    }
    __syncthreads();

    // ---- epilogue 3 ----
    {
        float biK = b3[colw] * KS;
        #pragma unroll
        for (int mt = 0; mt < 8; ++mt) {
            float t0 = tanh_pre(acc[mt][0] + biK);
            float t1 = tanh_pre(acc[mt][1] + biK);
            float t2 = tanh_pre(acc[mt][2] + biK);
            float t3 = tanh_pre(acc[mt][3] + biK);
            unsigned u01 = pack2bf(t0, t1);
            unsigned u23 = pack2bf(t2, t3);
            int rowb = (mt * 16 + quad * 4) * LDA + colw;
            A[rowb]           = (unsigned short)u01;
            A[rowb + LDA]     = (unsigned short)(u01 >> 16);
            A[rowb + 2 * LDA] = (unsigned short)u23;
            A[rowb + 3 * LDA] = (unsigned short)(u23 >> 16);
        }
    }
    __syncthreads();

    // ---- layer 4 + loss: 4 threads per point, 32 terms each ----
    {
        const int p  = tid >> 2;
        const int jb = (tid & 3) * 32;
        float s = 0.f;
        #pragma unroll
        for (int g = 0; g < 4; ++g) {
            uint4 u = *(const uint4*)&A[p * LDA + jb + g * 8];
            float4 wa = *(const float4*)(W4 + jb + g * 8);
            float4 wb = *(const float4*)(W4 + jb + g * 8 + 4);
            s += __uint_as_float(u.x << 16)          * wa.x;
            s += __uint_as_float(u.x & 0xffff0000u)  * wa.y;
            s += __uint_as_float(u.y << 16)          * wa.z;
            s += __uint_as_float(u.y & 0xffff0000u)  * wa.w;
            s += __uint_as_float(u.z << 16)          * wb.x;
            s += __uint_as_float(u.z & 0xffff0000u)  * wb.y;
            s += __uint_as_float(u.w << 16)          * wb.z;
            s += __uint_as_float(u.w & 0xffff0000u)  * wb.w;
        }
        s += __shfl_xor(s, 1, 64);
        s += __shfl_xor(s, 2, 64);
        float e2 = 0.f;
        if ((tid & 3) == 0) {
            float recon = s + b4[0];
            float img = images[(b << 16) + (r << 8) + c0 + p];
            float err = img - recon;
            e2 = err * err;
        }
        #pragma unroll
        for (int off = 4; off < 64; off <<= 1)
            e2 += __shfl_xor(e2, off, 64);
        if (lane == 0)
            atomicAdd(&partials[bid & 1023], e2);   // device-scope RMW, coherent (R2-proven)
    }

    // ---- fence-free last-block reduction ----
    // __syncthreads' barrier drain (vmcnt(0)) guarantees this block's partials
    // atomics reached the coherence point before the counter bump. NO fences.
    __syncthreads();
    if (tid == 0)
        isLastS = (atomicAdd(counter, 1u) == (unsigned)(gridDim.x - 1)) ? 1u : 0u;
    __syncthreads();
    if (isLastS) {
        // agent-scope relaxed atomic loads: cache-bypassing reads coherent with
        // the RMWs above; no L2 writeback/invalidate involved.
        float s = __hip_atomic_load(&partials[tid],       __ATOMIC_RELAXED, __HIP_MEMORY_SCOPE_AGENT)
                + __hip_atomic_load(&partials[tid + 512], __ATOMIC_RELAXED, __HIP_MEMORY_SCOPE_AGENT);
        #pragma unroll
        for (int off = 1; off < 64; off <<= 1)
            s += __shfl_xor(s, off, 64);
        if (lane == 0) red[w] = s;
        __syncthreads();
        if (tid == 0) {
            float tot = 0.f;
            #pragma unroll
            for (int i = 0; i < 8; ++i) tot += red[i];
            out[0] = tot * (1.f / 1048576.f);
        }
    }
}

extern "C" void kernel_launch(void* const* d_in, const int* in_sizes, int n_in,
                              void* d_out, int out_size, void* d_ws, size_t ws_size,
                              hipStream_t stream)
{
    const float* images = (const float*)d_in[0];
    const float* W1 = (const float*)d_in[1];
    const float* b1 = (const float*)d_in[2];
    const float* W2 = (const float*)d_in[3];
    const float* b2 = (const float*)d_in[4];
    const float* W3 = (const float*)d_in[5];
    const float* b3 = (const float*)d_in[6];
    const float* W4 = (const float*)d_in[7];
    const float* b4 = (const float*)d_in[8];
    const int*   np = (const int*)d_in[10];

    unsigned short* w2t = (unsigned short*)d_ws;                     // 32 KB
    unsigned short* w3t = w2t + 128 * 128;                           // 32 KB
    float* partials = (float*)((char*)d_ws + 65536);                 // 4 KB
    unsigned int* counter = (unsigned int*)((char*)d_ws + 65536 + 4096);

    prep_kernel<<<128, 256, 0, stream>>>(W2, W3, w2t, w3t, partials, counter);
    main_kernel<<<BATCH * 256 * 2, 512, 0, stream>>>(
        images, W1, b1, b2, b3, W4, b4, np, w2t, w3t, partials, counter, (float*)d_out);
}

// Round 8
// 200.886 us; speedup vs baseline: 1.2057x; 1.2057x over previous
//
#include <hip/hip_runtime.h>
#include <hip/hip_bf16.h>

// SurfaceLoss: 16x256x256 grid through 3->128->128->128->1 tanh MLP, MSE vs images.
// R8: (a) revert tanh to R6's measured-best exp2+rcp form (R7's bit-trick cost +19us
//     VALU issue: v_rcp is ~free on the trans pipe at this occupancy).
//     (b) layer-3 MFMA operand swap: mfma(W3frag, H2frag, acc) = H3^T with lane
//     layout [ch=quad*4+rg][point=l15] -> layer 4 fused in registers (tanh*W4,
//     quad-butterfly), deleting epilogue-3 stores + all layer-4 LDS/unpack VALU.
//     (c) biases folded into MFMA acc init (C=bias, not 0).
//     Keeps: R7 fence-free last-block reduction, (512,8), LDA 136, KS folding.

#define BATCH 16
#define LDA 136                 // padded LDS row stride (bf16 elems)
#define STEP (256.0f / 255.0f)  // linspace(-128,128,256) step
#define KS 2.8853900817779268f  // 2*log2(e): tanh(z) = 1 - 2/(exp2(KS*z)+1)

typedef __bf16 v8bf __attribute__((ext_vector_type(8)));
typedef float  v4f  __attribute__((ext_vector_type(4)));

__device__ __forceinline__ unsigned short f2bf(float f) {
    unsigned int u = __float_as_uint(f);
    unsigned int r = (u + 0x7fffu + ((u >> 16) & 1u)) >> 16;
    return (unsigned short)r;
}

#if __has_builtin(__builtin_amdgcn_cvt_pk_bf16_f32)
__device__ __forceinline__ unsigned int pack2bf(float a, float b) {
    auto p = __builtin_amdgcn_cvt_pk_bf16_f32(a, b);   // lo=a, hi=b
    union { decltype(p) v; unsigned int u; } c; c.v = p;
    return c.u;
}
#else
__device__ __forceinline__ unsigned int pack2bf(float a, float b) {
    return (unsigned)f2bf(a) | ((unsigned)f2bf(b) << 16);
}
#endif

// input pre-scaled by KS; R6 measured-best form. exp2(+big)->inf->rcp->0 exact.
__device__ __forceinline__ float tanh_pre(float zk) {
    float e = __builtin_amdgcn_exp2f(zk);
    float r = __builtin_amdgcn_rcpf(e + 1.f);
    return fmaf(-2.f, r, 1.f);
}

// ---- prep: W2,W3 (128x128 fp32 [k][n]) -> bf16 [n][k] pre-scaled by KS;
//      zero partials + counter ----
__global__ __launch_bounds__(256) void prep_kernel(
    const float* __restrict__ W2, const float* __restrict__ W3,
    unsigned short* __restrict__ w2t, unsigned short* __restrict__ w3t,
    float* __restrict__ partials, unsigned int* __restrict__ counter)
{
    int o = blockIdx.x * 256 + threadIdx.x;
    if (o < 1024) partials[o] = 0.f;
    if (o == 0) *counter = 0u;
    const float* src = (o < 16384) ? W2 : W3;
    unsigned short* dst = (o < 16384) ? w2t : w3t;
    int e = o & 16383;
    int k = e >> 7, n = e & 127;
    dst[n * 128 + k] = f2bf(src[e] * KS);
}

// ---- main: one block (512 thr, 8 waves) = 128 consecutive pixels of one image row ----
__global__ __launch_bounds__(512, 8) void main_kernel(
    const float* __restrict__ images,
    const float* __restrict__ W1, const float* __restrict__ b1,
    const float* __restrict__ b2, const float* __restrict__ b3,
    const float* __restrict__ W4, const float* __restrict__ b4,
    const int*   __restrict__ np,
    const unsigned short* __restrict__ w2t,
    const unsigned short* __restrict__ w3t,
    float* __restrict__ partials, unsigned int* __restrict__ counter,
    float* __restrict__ out)
{
    __shared__ unsigned short A[128 * LDA];
    __shared__ float P[8][128];       // per-wave partial dots (16 chs each) per point
    __shared__ float red[8];
    __shared__ unsigned int isLastS;

    const int tid  = threadIdx.x;
    const int lane = tid & 63;
    const int w    = tid >> 6;        // wave 0..7, owns 16 channels
    const int l15  = lane & 15;
    const int quad = lane >> 4;

    const int bid = blockIdx.x;
    const int b   = bid >> 9;          // 512 blocks per image
    const int rem = bid & 511;
    const int r   = rem >> 1;          // image row (x index)
    const int c0  = (rem & 1) << 7;    // y base

    const float tv = (float)(b + np[0] * BATCH);
    const float xv = -128.f + (float)r * STEP;

    // ---- layer 1 (fp32, pre-scaled by KS): each thread 4 cols x 8 points ----
    {
        const int lo = tid & 31, hi = tid >> 5;
        const int j0 = lo * 4, p0 = hi * 8;
        float4 wx = *(const float4*)(W1 + j0);
        float4 wy = *(const float4*)(W1 + 128 + j0);
        float4 wt = *(const float4*)(W1 + 256 + j0);
        float4 bb = *(const float4*)(b1 + j0);
        float cj0 = KS * fmaf(xv, wx.x, fmaf(tv, wt.x, bb.x));
        float cj1 = KS * fmaf(xv, wx.y, fmaf(tv, wt.y, bb.y));
        float cj2 = KS * fmaf(xv, wx.z, fmaf(tv, wt.z, bb.z));
        float cj3 = KS * fmaf(xv, wx.w, fmaf(tv, wt.w, bb.w));
        float wy0 = KS * wy.x, wy1 = KS * wy.y, wy2 = KS * wy.z, wy3 = KS * wy.w;
        #pragma unroll
        for (int pi = 0; pi < 8; ++pi) {
            const int p = p0 + pi;
            const float yv = fmaf((float)(c0 + p), STEP, -128.f);
            float t0 = tanh_pre(fmaf(yv, wy0, cj0));
            float t1 = tanh_pre(fmaf(yv, wy1, cj1));
            float t2 = tanh_pre(fmaf(yv, wy2, cj2));
            float t3 = tanh_pre(fmaf(yv, wy3, cj3));
            uint2 u = make_uint2(pack2bf(t0, t1), pack2bf(t2, t3));
            *(uint2*)&A[p * LDA + j0] = u;   // 8B store, conflict-free
        }
    }
    __syncthreads();

    const int colw = w * 16 + l15;     // this lane's output column (layer 2)

    // ---- W2 B-fragments from L2 ([n][k] layout, pre-scaled) ----
    v8bf wf[4];
    #pragma unroll
    for (int ks = 0; ks < 4; ++ks)
        wf[ks] = *(const v8bf*)(w2t + colw * 128 + ks * 32 + quad * 8);

    // ---- layer 2 MFMA: C = H1 @ W2K, acc init = KS*b2[col] (bias folded) ----
    v4f acc[8];
    {
        float biK = b2[colw] * KS;
        #pragma unroll
        for (int mt = 0; mt < 8; ++mt) acc[mt] = (v4f){biK, biK, biK, biK};
    }
    #pragma unroll
    for (int ks = 0; ks < 4; ++ks) {
        #pragma unroll
        for (int mt = 0; mt < 8; ++mt) {
            v8bf af = *(const v8bf*)&A[(mt * 16 + l15) * LDA + ks * 32 + quad * 8];
            acc[mt] = __builtin_amdgcn_mfma_f32_16x16x32_bf16(af, wf[ks], acc[mt], 0, 0, 0);
        }
    }

    // prefetch W3 A-fragments (row ch = colw, k-chunk = quad*8 — A-operand layout)
    v8bf w3f[4];
    #pragma unroll
    for (int ks = 0; ks < 4; ++ks)
        w3f[ks] = *(const v8bf*)(w3t + colw * 128 + ks * 32 + quad * 8);
    __syncthreads();   // all waves done reading A

    // ---- epilogue 2: tanh(acc) -> A (bias already in acc) ----
    #pragma unroll
    for (int mt = 0; mt < 8; ++mt) {
        float t0 = tanh_pre(acc[mt][0]);
        float t1 = tanh_pre(acc[mt][1]);
        float t2 = tanh_pre(acc[mt][2]);
        float t3 = tanh_pre(acc[mt][3]);
        unsigned u01 = pack2bf(t0, t1);
        unsigned u23 = pack2bf(t2, t3);
        int rowb = (mt * 16 + quad * 4) * LDA + colw;
        A[rowb]           = (unsigned short)u01;
        A[rowb + LDA]     = (unsigned short)(u01 >> 16);
        A[rowb + 2 * LDA] = (unsigned short)u23;
        A[rowb + 3 * LDA] = (unsigned short)(u23 >> 16);
    }
    __syncthreads();

    // ---- layer 3 MFMA, OPERAND-SWAPPED: D = W3K^T(16 chs) x H2^T = H3^T tile.
    //      A-op = w3f (row ch=l15-of-load=colw, k-chunk quad*8);
    //      B-op = H2 frag (col point=l15, k-chunk quad*8) — same LDS reads as before.
    //      D[ch = w*16 + quad*4+rg][point = mt*16 + l15], acc init = KS*b3[ch]. ----
    const int ch4 = w * 16 + quad * 4;           // this lane's 4 channels base
    {
        float4 b3q = *(const float4*)(b3 + ch4);
        v4f ini = (v4f){b3q.x * KS, b3q.y * KS, b3q.z * KS, b3q.w * KS};
        #pragma unroll
        for (int mt = 0; mt < 8; ++mt) acc[mt] = ini;
    }
    #pragma unroll
    for (int ks = 0; ks < 4; ++ks) {
        #pragma unroll
        for (int mt = 0; mt < 8; ++mt) {
            v8bf af = *(const v8bf*)&A[(mt * 16 + l15) * LDA + ks * 32 + quad * 8];
            acc[mt] = __builtin_amdgcn_mfma_f32_16x16x32_bf16(w3f[ks], af, acc[mt], 0, 0, 0);
        }
    }

    // ---- epilogue 3 fused with layer 4: s = sum_rg tanh(acc)*W4[ch], quad-butterfly ----
    {
        float4 w4q = *(const float4*)(W4 + ch4);
        #pragma unroll
        for (int mt = 0; mt < 8; ++mt) {
            float s;
            s  = tanh_pre(acc[mt][0]) * w4q.x;
            s  = fmaf(tanh_pre(acc[mt][1]), w4q.y, s);
            s  = fmaf(tanh_pre(acc[mt][2]), w4q.z, s);
            s  = fmaf(tanh_pre(acc[mt][3]), w4q.w, s);
            s += __shfl_xor(s, 16, 64);      // sum quads 0..3 (same point)
            s += __shfl_xor(s, 32, 64);
            if (quad == 0) P[w][mt * 16 + l15] = s;   // wave's 16-ch partial for point
        }
    }
    __syncthreads();

    // ---- loss: threads 0..127, one point each ----
    {
        float e2 = 0.f;
        if (tid < 128) {
            float s = b4[0];
            #pragma unroll
            for (int ww = 0; ww < 8; ++ww) s += P[ww][tid];
            float img = images[(b << 16) + (r << 8) + c0 + tid];
            float err = img - s;
            e2 = err * err;
        }
        #pragma unroll
        for (int off = 1; off < 64; off <<= 1)
            e2 += __shfl_xor(e2, off, 64);
        if (lane == 0 && tid < 128)
            atomicAdd(&partials[bid & 1023], e2);   // device-scope RMW (proven cheap)
    }

    // ---- fence-free last-block reduction (R7-proven) ----
    __syncthreads();
    if (tid == 0)
        isLastS = (atomicAdd(counter, 1u) == (unsigned)(gridDim.x - 1)) ? 1u : 0u;
    __syncthreads();
    if (isLastS) {
        float s = __hip_atomic_load(&partials[tid],       __ATOMIC_RELAXED, __HIP_MEMORY_SCOPE_AGENT)
                + __hip_atomic_load(&partials[tid + 512], __ATOMIC_RELAXED, __HIP_MEMORY_SCOPE_AGENT);
        #pragma unroll
        for (int off = 1; off < 64; off <<= 1)
            s += __shfl_xor(s, off, 64);
        if (lane == 0) red[w] = s;
        __syncthreads();
        if (tid == 0) {
            float tot = 0.f;
            #pragma unroll
            for (int i = 0; i < 8; ++i) tot += red[i];
            out[0] = tot * (1.f / 1048576.f);
        }
    }
}

extern "C" void kernel_launch(void* const* d_in, const int* in_sizes, int n_in,
                              void* d_out, int out_size, void* d_ws, size_t ws_size,
                              hipStream_t stream)
{
    const float* images = (const float*)d_in[0];
    const float* W1 = (const float*)d_in[1];
    const float* b1 = (const float*)d_in[2];
    const float* W2 = (const float*)d_in[3];
    const float* b2 = (const float*)d_in[4];
    const float* W3 = (const float*)d_in[5];
    const float* b3 = (const float*)d_in[6];
    const float* W4 = (const float*)d_in[7];
    const float* b4 = (const float*)d_in[8];
    const int*   np = (const int*)d_in[10];

    unsigned short* w2t = (unsigned short*)d_ws;                     // 32 KB
    unsigned short* w3t = w2t + 128 * 128;                           // 32 KB
    float* partials = (float*)((char*)d_ws + 65536);                 // 4 KB
    unsigned int* counter = (unsigned int*)((char*)d_ws + 65536 + 4096);

    prep_kernel<<<128, 256, 0, stream>>>(W2, W3, w2t, w3t, partials, counter);
    main_kernel<<<BATCH * 256 * 2, 512, 0, stream>>>(
        images, W1, b1, b2, b3, W4, b4, np, w2t, w3t, partials, counter, (float*)d_out);
}

// Round 9
// 199.252 us; speedup vs baseline: 1.2155x; 1.0082x over previous
//
#include <hip/hip_runtime.h>
#include <hip/hip_bf16.h>

// SurfaceLoss: 16x256x256 grid through 3->128->128->128->1 tanh MLP, MSE vs images.
// R9: layer-2 MFMA operand swap too (both layers now D[ch][point]):
//     W2 frag bytes already A-operand layout, so only arg order + bias init change;
//     epilogue-2 becomes ONE ds_write_b64 of 4 consecutive-ch bf16 per point
//     (8 stores/lane vs 32 scattered b16), layer-3 reads unchanged.
//     Keeps: R8 layer-3 swap + fused layer-4, exp2+rcp tanh (measured best),
//     fence-free last-block reduction, (512,8), LDA 136, KS folding.

#define BATCH 16
#define LDA 136                 // padded LDS row stride (bf16 elems)
#define STEP (256.0f / 255.0f)  // linspace(-128,128,256) step
#define KS 2.8853900817779268f  // 2*log2(e): tanh(z) = 1 - 2/(exp2(KS*z)+1)

typedef __bf16 v8bf __attribute__((ext_vector_type(8)));
typedef float  v4f  __attribute__((ext_vector_type(4)));

__device__ __forceinline__ unsigned short f2bf(float f) {
    unsigned int u = __float_as_uint(f);
    unsigned int r = (u + 0x7fffu + ((u >> 16) & 1u)) >> 16;
    return (unsigned short)r;
}

#if __has_builtin(__builtin_amdgcn_cvt_pk_bf16_f32)
__device__ __forceinline__ unsigned int pack2bf(float a, float b) {
    auto p = __builtin_amdgcn_cvt_pk_bf16_f32(a, b);   // lo=a, hi=b
    union { decltype(p) v; unsigned int u; } c; c.v = p;
    return c.u;
}
#else
__device__ __forceinline__ unsigned int pack2bf(float a, float b) {
    return (unsigned)f2bf(a) | ((unsigned)f2bf(b) << 16);
}
#endif

// input pre-scaled by KS; R6 measured-best form. exp2(+big)->inf->rcp->0 exact.
__device__ __forceinline__ float tanh_pre(float zk) {
    float e = __builtin_amdgcn_exp2f(zk);
    float r = __builtin_amdgcn_rcpf(e + 1.f);
    return fmaf(-2.f, r, 1.f);
}

// ---- prep: W2,W3 (128x128 fp32 [k][n]) -> bf16 [n][k] pre-scaled by KS;
//      zero partials + counter ----
__global__ __launch_bounds__(256) void prep_kernel(
    const float* __restrict__ W2, const float* __restrict__ W3,
    unsigned short* __restrict__ w2t, unsigned short* __restrict__ w3t,
    float* __restrict__ partials, unsigned int* __restrict__ counter)
{
    int o = blockIdx.x * 256 + threadIdx.x;
    if (o < 1024) partials[o] = 0.f;
    if (o == 0) *counter = 0u;
    const float* src = (o < 16384) ? W2 : W3;
    unsigned short* dst = (o < 16384) ? w2t : w3t;
    int e = o & 16383;
    int k = e >> 7, n = e & 127;
    dst[n * 128 + k] = f2bf(src[e] * KS);
}

// ---- main: one block (512 thr, 8 waves) = 128 consecutive pixels of one image row ----
__global__ __launch_bounds__(512, 8) void main_kernel(
    const float* __restrict__ images,
    const float* __restrict__ W1, const float* __restrict__ b1,
    const float* __restrict__ b2, const float* __restrict__ b3,
    const float* __restrict__ W4, const float* __restrict__ b4,
    const int*   __restrict__ np,
    const unsigned short* __restrict__ w2t,
    const unsigned short* __restrict__ w3t,
    float* __restrict__ partials, unsigned int* __restrict__ counter,
    float* __restrict__ out)
{
    __shared__ unsigned short A[128 * LDA];
    __shared__ float P[8][128];       // per-wave partial dots (16 chs each) per point
    __shared__ float red[8];
    __shared__ unsigned int isLastS;

    const int tid  = threadIdx.x;
    const int lane = tid & 63;
    const int w    = tid >> 6;        // wave 0..7, owns 16 channels
    const int l15  = lane & 15;
    const int quad = lane >> 4;

    const int bid = blockIdx.x;
    const int b   = bid >> 9;          // 512 blocks per image
    const int rem = bid & 511;
    const int r   = rem >> 1;          // image row (x index)
    const int c0  = (rem & 1) << 7;    // y base

    const float tv = (float)(b + np[0] * BATCH);
    const float xv = -128.f + (float)r * STEP;

    // ---- layer 1 (fp32, pre-scaled by KS): each thread 4 cols x 8 points ----
    {
        const int lo = tid & 31, hi = tid >> 5;
        const int j0 = lo * 4, p0 = hi * 8;
        float4 wx = *(const float4*)(W1 + j0);
        float4 wy = *(const float4*)(W1 + 128 + j0);
        float4 wt = *(const float4*)(W1 + 256 + j0);
        float4 bb = *(const float4*)(b1 + j0);
        float cj0 = KS * fmaf(xv, wx.x, fmaf(tv, wt.x, bb.x));
        float cj1 = KS * fmaf(xv, wx.y, fmaf(tv, wt.y, bb.y));
        float cj2 = KS * fmaf(xv, wx.z, fmaf(tv, wt.z, bb.z));
        float cj3 = KS * fmaf(xv, wx.w, fmaf(tv, wt.w, bb.w));
        float wy0 = KS * wy.x, wy1 = KS * wy.y, wy2 = KS * wy.z, wy3 = KS * wy.w;
        #pragma unroll
        for (int pi = 0; pi < 8; ++pi) {
            const int p = p0 + pi;
            const float yv = fmaf((float)(c0 + p), STEP, -128.f);
            float t0 = tanh_pre(fmaf(yv, wy0, cj0));
            float t1 = tanh_pre(fmaf(yv, wy1, cj1));
            float t2 = tanh_pre(fmaf(yv, wy2, cj2));
            float t3 = tanh_pre(fmaf(yv, wy3, cj3));
            uint2 u = make_uint2(pack2bf(t0, t1), pack2bf(t2, t3));
            *(uint2*)&A[p * LDA + j0] = u;   // 8B store, conflict-free
        }
    }
    __syncthreads();

    const int colw = w * 16 + l15;     // this lane's channel row (A-operand m index)
    const int ch4  = w * 16 + quad * 4; // this lane's 4-channel base in C/D layout

    // ---- W2 A-fragments from L2 ([n][k] layout = A-op [m=ch][k], pre-scaled) ----
    v8bf wf[4];
    #pragma unroll
    for (int ks = 0; ks < 4; ++ks)
        wf[ks] = *(const v8bf*)(w2t + colw * 128 + ks * 32 + quad * 8);

    // ---- layer 2 MFMA, swapped: D = W2K^T x H1^T -> D[ch][point];
    //      acc init = KS*b2[ch] (bias folded) ----
    v4f acc[8];
    {
        float4 b2q = *(const float4*)(b2 + ch4);
        v4f ini = (v4f){b2q.x * KS, b2q.y * KS, b2q.z * KS, b2q.w * KS};
        #pragma unroll
        for (int mt = 0; mt < 8; ++mt) acc[mt] = ini;
    }
    #pragma unroll
    for (int ks = 0; ks < 4; ++ks) {
        #pragma unroll
        for (int mt = 0; mt < 8; ++mt) {
            v8bf af = *(const v8bf*)&A[(mt * 16 + l15) * LDA + ks * 32 + quad * 8];
            acc[mt] = __builtin_amdgcn_mfma_f32_16x16x32_bf16(wf[ks], af, acc[mt], 0, 0, 0);
        }
    }

    // prefetch W3 A-fragments (same layout)
    v8bf w3f[4];
    #pragma unroll
    for (int ks = 0; ks < 4; ++ks)
        w3f[ks] = *(const v8bf*)(w3t + colw * 128 + ks * 32 + quad * 8);
    __syncthreads();   // all waves done reading A (H1)

    // ---- epilogue 2: tanh(acc) -> A as H2[point][ch], ONE b64 store per mt ----
    #pragma unroll
    for (int mt = 0; mt < 8; ++mt) {
        float t0 = tanh_pre(acc[mt][0]);
        float t1 = tanh_pre(acc[mt][1]);
        float t2 = tanh_pre(acc[mt][2]);
        float t3 = tanh_pre(acc[mt][3]);
        uint2 u = make_uint2(pack2bf(t0, t1), pack2bf(t2, t3));
        *(uint2*)&A[(mt * 16 + l15) * LDA + ch4] = u;   // 4 consecutive ch, 8B aligned
    }
    __syncthreads();

    // ---- layer 3 MFMA, swapped (R8-proven): D[ch][point], acc init = KS*b3[ch] ----
    {
        float4 b3q = *(const float4*)(b3 + ch4);
        v4f ini = (v4f){b3q.x * KS, b3q.y * KS, b3q.z * KS, b3q.w * KS};
        #pragma unroll
        for (int mt = 0; mt < 8; ++mt) acc[mt] = ini;
    }
    #pragma unroll
    for (int ks = 0; ks < 4; ++ks) {
        #pragma unroll
        for (int mt = 0; mt < 8; ++mt) {
            v8bf af = *(const v8bf*)&A[(mt * 16 + l15) * LDA + ks * 32 + quad * 8];
            acc[mt] = __builtin_amdgcn_mfma_f32_16x16x32_bf16(w3f[ks], af, acc[mt], 0, 0, 0);
        }
    }

    // ---- epilogue 3 fused with layer 4: s = sum_rg tanh(acc)*W4[ch], quad-butterfly ----
    {
        float4 w4q = *(const float4*)(W4 + ch4);
        #pragma unroll
        for (int mt = 0; mt < 8; ++mt) {
            float s;
            s  = tanh_pre(acc[mt][0]) * w4q.x;
            s  = fmaf(tanh_pre(acc[mt][1]), w4q.y, s);
            s  = fmaf(tanh_pre(acc[mt][2]), w4q.z, s);
            s  = fmaf(tanh_pre(acc[mt][3]), w4q.w, s);
            s += __shfl_xor(s, 16, 64);      // sum quads 0..3 (same point)
            s += __shfl_xor(s, 32, 64);
            if (quad == 0) P[w][mt * 16 + l15] = s;   // wave's 16-ch partial for point
        }
    }
    __syncthreads();

    // ---- loss: threads 0..127, one point each ----
    {
        float e2 = 0.f;
        if (tid < 128) {
            float s = b4[0];
            #pragma unroll
            for (int ww = 0; ww < 8; ++ww) s += P[ww][tid];
            float img = images[(b << 16) + (r << 8) + c0 + tid];
            float err = img - s;
            e2 = err * err;
        }
        #pragma unroll
        for (int off = 1; off < 64; off <<= 1)
            e2 += __shfl_xor(e2, off, 64);
        if (lane == 0 && tid < 128)
            atomicAdd(&partials[bid & 1023], e2);   // device-scope RMW (proven cheap)
    }

    // ---- fence-free last-block reduction (R7-proven) ----
    __syncthreads();
    if (tid == 0)
        isLastS = (atomicAdd(counter, 1u) == (unsigned)(gridDim.x - 1)) ? 1u : 0u;
    __syncthreads();
    if (isLastS) {
        float s = __hip_atomic_load(&partials[tid],       __ATOMIC_RELAXED, __HIP_MEMORY_SCOPE_AGENT)
                + __hip_atomic_load(&partials[tid + 512], __ATOMIC_RELAXED, __HIP_MEMORY_SCOPE_AGENT);
        #pragma unroll
        for (int off = 1; off < 64; off <<= 1)
            s += __shfl_xor(s, off, 64);
        if (lane == 0) red[w] = s;
        __syncthreads();
        if (tid == 0) {
            float tot = 0.f;
            #pragma unroll
            for (int i = 0; i < 8; ++i) tot += red[i];
            out[0] = tot * (1.f / 1048576.f);
        }
    }
}

extern "C" void kernel_launch(void* const* d_in, const int* in_sizes, int n_in,
                              void* d_out, int out_size, void* d_ws, size_t ws_size,
                              hipStream_t stream)
{
    const float* images = (const float*)d_in[0];
    const float* W1 = (const float*)d_in[1];
    const float* b1 = (const float*)d_in[2];
    const float* W2 = (const float*)d_in[3];
    const float* b2 = (const float*)d_in[4];
    const float* W3 = (const float*)d_in[5];
    const float* b3 = (const float*)d_in[6];
    const float* W4 = (const float*)d_in[7];
    const float* b4 = (const float*)d_in[8];
    const int*   np = (const int*)d_in[10];

    unsigned short* w2t = (unsigned short*)d_ws;                     // 32 KB
    unsigned short* w3t = w2t + 128 * 128;                           // 32 KB
    float* partials = (float*)((char*)d_ws + 65536);                 // 4 KB
    unsigned int* counter = (unsigned int*)((char*)d_ws + 65536 + 4096);

    prep_kernel<<<128, 256, 0, stream>>>(W2, W3, w2t, w3t, partials, counter);
    main_kernel<<<BATCH * 256 * 2, 512, 0, stream>>>(
        images, W1, b1, b2, b3, W4, b4, np, w2t, w3t, partials, counter, (float*)d_out);
}

// Round 10
// 194.695 us; speedup vs baseline: 1.2440x; 1.0234x over previous
//
#include <hip/hip_runtime.h>
#include <hip/hip_bf16.h>

// SurfaceLoss: 16x256x256 grid through 3->128->128->128->1 tanh MLP, MSE vs images.
// R10: (a) pack2bf via single v_perm_b32 (bf16 TRUNCATION — 1 slot guaranteed;
//      the old __has_builtin(cvt_pk_bf16) guard may have silently fallen back to a
//      ~10-inst manual pack = the prime suspect for ~16us of unexplained VALU).
//      (b) layer-1 incremental z update (z += STEP*wyK, kills per-point cvt+fma).
//      Frozen: R9 dual operand-swapped MFMA (D[ch][point] both layers), fused
//      epi3+layer4, exp2+rcp tanh (measured best), fence-free last-block
//      reduction, (512,8), LDA 136, KS folding.

#define BATCH 16
#define LDA 136                 // padded LDS row stride (bf16 elems)
#define STEP (256.0f / 255.0f)  // linspace(-128,128,256) step
#define KS 2.8853900817779268f  // 2*log2(e): tanh(z) = 1 - 2/(exp2(KS*z)+1)

typedef __bf16 v8bf __attribute__((ext_vector_type(8)));
typedef float  v4f  __attribute__((ext_vector_type(4)));

__device__ __forceinline__ unsigned short f2bf(float f) {   // round-nearest (prep only)
    unsigned int u = __float_as_uint(f);
    unsigned int r = (u + 0x7fffu + ((u >> 16) & 1u)) >> 16;
    return (unsigned short)r;
}

// hot-path pack: {hi16(b), hi16(a)} in ONE v_perm_b32 (bf16 truncation).
#if __has_builtin(__builtin_amdgcn_perm)
__device__ __forceinline__ unsigned int pack2bf(float a, float b) {
    return __builtin_amdgcn_perm(__float_as_uint(b), __float_as_uint(a), 0x07060302u);
}
#else
__device__ __forceinline__ unsigned int pack2bf(float a, float b) {
    return (__float_as_uint(a) >> 16) | (__float_as_uint(b) & 0xffff0000u);
}
#endif

// input pre-scaled by KS; R6 measured-best form. exp2(+big)->inf->rcp->0 exact.
__device__ __forceinline__ float tanh_pre(float zk) {
    float e = __builtin_amdgcn_exp2f(zk);
    float r = __builtin_amdgcn_rcpf(e + 1.f);
    return fmaf(-2.f, r, 1.f);
}

// ---- prep: W2,W3 (128x128 fp32 [k][n]) -> bf16 [n][k] pre-scaled by KS;
//      zero partials + counter ----
__global__ __launch_bounds__(256) void prep_kernel(
    const float* __restrict__ W2, const float* __restrict__ W3,
    unsigned short* __restrict__ w2t, unsigned short* __restrict__ w3t,
    float* __restrict__ partials, unsigned int* __restrict__ counter)
{
    int o = blockIdx.x * 256 + threadIdx.x;
    if (o < 1024) partials[o] = 0.f;
    if (o == 0) *counter = 0u;
    const float* src = (o < 16384) ? W2 : W3;
    unsigned short* dst = (o < 16384) ? w2t : w3t;
    int e = o & 16383;
    int k = e >> 7, n = e & 127;
    dst[n * 128 + k] = f2bf(src[e] * KS);
}

// ---- main: one block (512 thr, 8 waves) = 128 consecutive pixels of one image row ----
__global__ __launch_bounds__(512, 8) void main_kernel(
    const float* __restrict__ images,
    const float* __restrict__ W1, const float* __restrict__ b1,
    const float* __restrict__ b2, const float* __restrict__ b3,
    const float* __restrict__ W4, const float* __restrict__ b4,
    const int*   __restrict__ np,
    const unsigned short* __restrict__ w2t,
    const unsigned short* __restrict__ w3t,
    float* __restrict__ partials, unsigned int* __restrict__ counter,
    float* __restrict__ out)
{
    __shared__ unsigned short A[128 * LDA];
    __shared__ float P[8][128];       // per-wave partial dots (16 chs each) per point
    __shared__ float red[8];
    __shared__ unsigned int isLastS;

    const int tid  = threadIdx.x;
    const int lane = tid & 63;
    const int w    = tid >> 6;        // wave 0..7, owns 16 channels
    const int l15  = lane & 15;
    const int quad = lane >> 4;

    const int bid = blockIdx.x;
    const int b   = bid >> 9;          // 512 blocks per image
    const int rem = bid & 511;
    const int r   = rem >> 1;          // image row (x index)
    const int c0  = (rem & 1) << 7;    // y base

    const float tv = (float)(b + np[0] * BATCH);
    const float xv = -128.f + (float)r * STEP;

    // ---- layer 1 (fp32, pre-scaled by KS): 4 cols x 8 points, incremental z ----
    {
        const int lo = tid & 31, hi = tid >> 5;
        const int j0 = lo * 4, p0 = hi * 8;
        float4 wx = *(const float4*)(W1 + j0);
        float4 wy = *(const float4*)(W1 + 128 + j0);
        float4 wt = *(const float4*)(W1 + 256 + j0);
        float4 bb = *(const float4*)(b1 + j0);
        float wy0 = KS * wy.x, wy1 = KS * wy.y, wy2 = KS * wy.z, wy3 = KS * wy.w;
        const float yv0 = fmaf((float)(c0 + p0), STEP, -128.f);
        float z0 = fmaf(yv0, wy0, KS * fmaf(xv, wx.x, fmaf(tv, wt.x, bb.x)));
        float z1 = fmaf(yv0, wy1, KS * fmaf(xv, wx.y, fmaf(tv, wt.y, bb.y)));
        float z2 = fmaf(yv0, wy2, KS * fmaf(xv, wx.z, fmaf(tv, wt.z, bb.z)));
        float z3 = fmaf(yv0, wy3, KS * fmaf(xv, wx.w, fmaf(tv, wt.w, bb.w)));
        const float d0 = STEP * wy0, d1 = STEP * wy1, d2 = STEP * wy2, d3 = STEP * wy3;
        #pragma unroll
        for (int pi = 0; pi < 8; ++pi) {
            uint2 u = make_uint2(pack2bf(tanh_pre(z0), tanh_pre(z1)),
                                 pack2bf(tanh_pre(z2), tanh_pre(z3)));
            *(uint2*)&A[(p0 + pi) * LDA + j0] = u;   // 8B store, conflict-free
            z0 += d0; z1 += d1; z2 += d2; z3 += d3;
        }
    }
    __syncthreads();

    const int colw = w * 16 + l15;     // this lane's channel row (A-operand m index)
    const int ch4  = w * 16 + quad * 4; // this lane's 4-channel base in C/D layout

    // ---- W2 A-fragments from L2 ([n][k] layout = A-op [m=ch][k], pre-scaled) ----
    v8bf wf[4];
    #pragma unroll
    for (int ks = 0; ks < 4; ++ks)
        wf[ks] = *(const v8bf*)(w2t + colw * 128 + ks * 32 + quad * 8);

    // ---- layer 2 MFMA, swapped: D = W2K^T x H1^T -> D[ch][point];
    //      acc init = KS*b2[ch] (bias folded) ----
    v4f acc[8];
    {
        float4 b2q = *(const float4*)(b2 + ch4);
        v4f ini = (v4f){b2q.x * KS, b2q.y * KS, b2q.z * KS, b2q.w * KS};
        #pragma unroll
        for (int mt = 0; mt < 8; ++mt) acc[mt] = ini;
    }
    #pragma unroll
    for (int ks = 0; ks < 4; ++ks) {
        #pragma unroll
        for (int mt = 0; mt < 8; ++mt) {
            v8bf af = *(const v8bf*)&A[(mt * 16 + l15) * LDA + ks * 32 + quad * 8];
            acc[mt] = __builtin_amdgcn_mfma_f32_16x16x32_bf16(wf[ks], af, acc[mt], 0, 0, 0);
        }
    }

    // prefetch W3 A-fragments (same layout)
    v8bf w3f[4];
    #pragma unroll
    for (int ks = 0; ks < 4; ++ks)
        w3f[ks] = *(const v8bf*)(w3t + colw * 128 + ks * 32 + quad * 8);
    __syncthreads();   // all waves done reading A (H1)

    // ---- epilogue 2: tanh(acc) -> A as H2[point][ch], ONE b64 store per mt ----
    #pragma unroll
    for (int mt = 0; mt < 8; ++mt) {
        uint2 u = make_uint2(pack2bf(tanh_pre(acc[mt][0]), tanh_pre(acc[mt][1])),
                             pack2bf(tanh_pre(acc[mt][2]), tanh_pre(acc[mt][3])));
        *(uint2*)&A[(mt * 16 + l15) * LDA + ch4] = u;   // 4 consecutive ch, 8B aligned
    }
    __syncthreads();

    // ---- layer 3 MFMA, swapped: D[ch][point], acc init = KS*b3[ch] ----
    {
        float4 b3q = *(const float4*)(b3 + ch4);
        v4f ini = (v4f){b3q.x * KS, b3q.y * KS, b3q.z * KS, b3q.w * KS};
        #pragma unroll
        for (int mt = 0; mt < 8; ++mt) acc[mt] = ini;
    }
    #pragma unroll
    for (int ks = 0; ks < 4; ++ks) {
        #pragma unroll
        for (int mt = 0; mt < 8; ++mt) {
            v8bf af = *(const v8bf*)&A[(mt * 16 + l15) * LDA + ks * 32 + quad * 8];
            acc[mt] = __builtin_amdgcn_mfma_f32_16x16x32_bf16(w3f[ks], af, acc[mt], 0, 0, 0);
        }
    }

    // ---- epilogue 3 fused with layer 4: s = sum_rg tanh(acc)*W4[ch], quad-butterfly ----
    {
        float4 w4q = *(const float4*)(W4 + ch4);
        #pragma unroll
        for (int mt = 0; mt < 8; ++mt) {
            float s;
            s  = tanh_pre(acc[mt][0]) * w4q.x;
            s  = fmaf(tanh_pre(acc[mt][1]), w4q.y, s);
            s  = fmaf(tanh_pre(acc[mt][2]), w4q.z, s);
            s  = fmaf(tanh_pre(acc[mt][3]), w4q.w, s);
            s += __shfl_xor(s, 16, 64);      // sum quads 0..3 (same point)
            s += __shfl_xor(s, 32, 64);
            if (quad == 0) P[w][mt * 16 + l15] = s;   // wave's 16-ch partial for point
        }
    }
    __syncthreads();

    // ---- loss: threads 0..127, one point each ----
    {
        float e2 = 0.f;
        if (tid < 128) {
            float s = b4[0];
            #pragma unroll
            for (int ww = 0; ww < 8; ++ww) s += P[ww][tid];
            float img = images[(b << 16) + (r << 8) + c0 + tid];
            float err = img - s;
            e2 = err * err;
        }
        #pragma unroll
        for (int off = 1; off < 64; off <<= 1)
            e2 += __shfl_xor(e2, off, 64);
        if (lane == 0 && tid < 128)
            atomicAdd(&partials[bid & 1023], e2);   // device-scope RMW (proven cheap)
    }

    // ---- fence-free last-block reduction (R7-proven) ----
    __syncthreads();
    if (tid == 0)
        isLastS = (atomicAdd(counter, 1u) == (unsigned)(gridDim.x - 1)) ? 1u : 0u;
    __syncthreads();
    if (isLastS) {
        float s = __hip_atomic_load(&partials[tid],       __ATOMIC_RELAXED, __HIP_MEMORY_SCOPE_AGENT)
                + __hip_atomic_load(&partials[tid + 512], __ATOMIC_RELAXED, __HIP_MEMORY_SCOPE_AGENT);
        #pragma unroll
        for (int off = 1; off < 64; off <<= 1)
            s += __shfl_xor(s, off, 64);
        if (lane == 0) red[w] = s;
        __syncthreads();
        if (tid == 0) {
            float tot = 0.f;
            #pragma unroll
            for (int i = 0; i < 8; ++i) tot += red[i];
            out[0] = tot * (1.f / 1048576.f);
        }
    }
}

extern "C" void kernel_launch(void* const* d_in, const int* in_sizes, int n_in,
                              void* d_out, int out_size, void* d_ws, size_t ws_size,
                              hipStream_t stream)
{
    const float* images = (const float*)d_in[0];
    const float* W1 = (const float*)d_in[1];
    const float* b1 = (const float*)d_in[2];
    const float* W2 = (const float*)d_in[3];
    const float* b2 = (const float*)d_in[4];
    const float* W3 = (const float*)d_in[5];
    const float* b3 = (const float*)d_in[6];
    const float* W4 = (const float*)d_in[7];
    const float* b4 = (const float*)d_in[8];
    const int*   np = (const int*)d_in[10];

    unsigned short* w2t = (unsigned short*)d_ws;                     // 32 KB
    unsigned short* w3t = w2t + 128 * 128;                           // 32 KB
    float* partials = (float*)((char*)d_ws + 65536);                 // 4 KB
    unsigned int* counter = (unsigned int*)((char*)d_ws + 65536 + 4096);

    prep_kernel<<<128, 256, 0, stream>>>(W2, W3, w2t, w3t, partials, counter);
    main_kernel<<<BATCH * 256 * 2, 512, 0, stream>>>(
        images, W1, b1, b2, b3, W4, b4, np, w2t, w3t, partials, counter, (float*)d_out);
}